// Round 13
// baseline (419.490 us; speedup 1.0000x reference)
//
#include <hip/hip_runtime.h>
#include <stdint.h>

#define SLEN  512
#define BATCH 256
#define NTAGS 128
#define NTHR  1024   // j = tid>>3 (0..127), h = tid&7 -> 16 waves, 4/SIMD

// Cross-lane combine stages (validated bit-exact r5-r11)
__device__ __forceinline__ int dpp_qperm_b1(int x) {  // lane <- lane^1
    return __builtin_amdgcn_update_dpp(0, x, 0xB1, 0xF, 0xF, true);
}
__device__ __forceinline__ int dpp_qperm_4e(int x) {  // lane <- lane^2
    return __builtin_amdgcn_update_dpp(0, x, 0x4E, 0xF, 0xF, true);
}
__device__ __forceinline__ int swz_xor4(int x) {      // lane <- lane^4
    return __builtin_amdgcn_ds_swizzle(x, 0x101F);
}

__device__ __forceinline__ float combine_max8(float v) {
    float vo = __int_as_float(dpp_qperm_b1(__float_as_int(v))); v = fmaxf(v, vo);
    vo = __int_as_float(dpp_qperm_4e(__float_as_int(v)));       v = fmaxf(v, vo);
    vo = __int_as_float(swz_xor4(__float_as_int(v)));           v = fmaxf(v, vo);
    return v;
}
__device__ __forceinline__ float combine_min8(float v) {
    float vo = __int_as_float(dpp_qperm_b1(__float_as_int(v))); v = fminf(v, vo);
    vo = __int_as_float(dpp_qperm_4e(__float_as_int(v)));       v = fminf(v, vo);
    vo = __int_as_float(swz_xor4(__float_as_int(v)));           v = fminf(v, vo);
    return v;
}

// ---- packed 2xf32 VOP3P (gfx90a+): add/fma only (pk_max/min DO NOT exist) ----
__device__ __forceinline__ uint64_t pk2(float lo, float hi) {
    union { float f[2]; uint64_t u; } x; x.f[0] = lo; x.f[1] = hi; return x.u;
}
__device__ __forceinline__ float pklo(uint64_t a) { return __uint_as_float((unsigned)a); }
__device__ __forceinline__ float pkhi(uint64_t a) { return __uint_as_float((unsigned)(a >> 32)); }
__device__ __forceinline__ uint64_t pk_add(uint64_t a, uint64_t b) {
    uint64_t d; asm("v_pk_add_f32 %0, %1, %2" : "=v"(d) : "v"(a), "v"(b)); return d;
}
__device__ __forceinline__ uint64_t pk_fma(uint64_t a, uint64_t b, uint64_t c) {
    uint64_t d; asm("v_pk_fma_f32 %0, %1, %2, %3" : "=v"(d) : "v"(a), "v"(b), "v"(c)); return d;
}
// 3-input max/min: single VALU inst (gfx950 ISA sec.3)
__device__ __forceinline__ float max3(float a, float b, float c) {
    float d; asm("v_max3_f32 %0, %1, %2, %3" : "=v"(d) : "v"(a), "v"(b), "v"(c)); return d;
}
__device__ __forceinline__ float min3(float a, float b, float c) {
    float d; asm("v_min3_f32 %0, %1, %2, %3" : "=v"(d) : "v"(a), "v"(b), "v"(c)); return d;
}

__global__ __launch_bounds__(NTHR, 4) void viterbi_kernel(
    const float* __restrict__ em,      // [S,B,T]
    const int*   __restrict__ mask,    // [S,B]
    const float* __restrict__ start_t, // [T]
    const float* __restrict__ end_t,   // [T]
    const float* __restrict__ trans,   // [T,T]
    float* __restrict__ out)           // [B*S] tags (as float), then [B] scores
{
    const int b    = blockIdx.x;
    const int tid  = threadIdx.x;
    const int j    = tid >> 3;         // 0..127
    const int h    = tid & 7;          // 0..7
    const int base = h << 4;           // h*16
    const bool writer = (h == 0);
    const int jslot = j + (j >> 4) * 4;   // chunk j>>4 at float offset (j>>4)*20

    __shared__ __align__(16) float scbuf[2][8 * 20];
    __shared__ float fin[NTAGS];
    __shared__ int   maskv[SLEN];
    __shared__ unsigned char hist[SLEN - 1][NTAGS];   // 65408 B
    __shared__ unsigned char exitc[8][NTAGS];
    __shared__ unsigned char st_tags[8];
    __shared__ unsigned char tagseq[SLEN];
    __shared__ float bestval_s;
    __shared__ int   bestj_s;

    // trans pairs: trP_m = (trans[base+2m][j], trans[base+2m+1][j])
    const float* trp = trans + (size_t)base * NTAGS + j;
    const uint64_t trP0 = pk2(trp[ 0*NTAGS], trp[ 1*NTAGS]);
    const uint64_t trP1 = pk2(trp[ 2*NTAGS], trp[ 3*NTAGS]);
    const uint64_t trP2 = pk2(trp[ 4*NTAGS], trp[ 5*NTAGS]);
    const uint64_t trP3 = pk2(trp[ 6*NTAGS], trp[ 7*NTAGS]);
    const uint64_t trP4 = pk2(trp[ 8*NTAGS], trp[ 9*NTAGS]);
    const uint64_t trP5 = pk2(trp[10*NTAGS], trp[11*NTAGS]);
    const uint64_t trP6 = pk2(trp[12*NTAGS], trp[13*NTAGS]);
    const uint64_t trP7 = pk2(trp[14*NTAGS], trp[15*NTAGS]);

    // global-index pairs (float-encoded), and the -1e12 penalty pair
    const uint64_t kP0 = pk2((float)(base +  0), (float)(base +  1));
    const uint64_t kP1 = pk2((float)(base +  2), (float)(base +  3));
    const uint64_t kP2 = pk2((float)(base +  4), (float)(base +  5));
    const uint64_t kP3 = pk2((float)(base +  6), (float)(base +  7));
    const uint64_t kP4 = pk2((float)(base +  8), (float)(base +  9));
    const uint64_t kP5 = pk2((float)(base + 10), (float)(base + 11));
    const uint64_t kP6 = pk2((float)(base + 12), (float)(base + 13));
    const uint64_t kP7 = pk2((float)(base + 14), (float)(base + 15));
    const uint64_t negH = pk2(-1e12f, -1e12f);

    if (tid < SLEN)
        maskv[tid] = mask[tid * BATCH + b];

    float scj = 0.f;
    if (writer) {
        scj = start_t[j] + em[(size_t)b * NTAGS + j];   // exact ref associativity
        scbuf[0][jslot] = scj;
    }
    __syncthreads();

    const float* emp = em + (size_t)BATCH * NTAGS + (size_t)b * NTAGS + j; // t=1
    float em_next = *emp;

    int p = 0;
    for (int t = 1; t < SLEN; ++t) {
        const float em_cur = em_next;
        if (t + 1 < SLEN) { emp += BATCH * NTAGS; em_next = *emp; }

        // 16 sc values as 8 adjacent pairs (4 broadcast b128 reads)
        const float4* sq = (const float4*)&scbuf[p][h * 20];
        const float4 q0 = sq[0], q1 = sq[1], q2 = sq[2], q3 = sq[3];

        // c_k = fl(fl(sc+tr)+em): 2 candidates per v_pk_add_f32 (bit-exact per half)
        const uint64_t emP = pk2(em_cur, em_cur);
        const uint64_t c0 = pk_add(pk_add(pk2(q0.x, q0.y), trP0), emP);
        const uint64_t c1 = pk_add(pk_add(pk2(q0.z, q0.w), trP1), emP);
        const uint64_t c2 = pk_add(pk_add(pk2(q1.x, q1.y), trP2), emP);
        const uint64_t c3 = pk_add(pk_add(pk2(q1.z, q1.w), trP3), emP);
        const uint64_t c4 = pk_add(pk_add(pk2(q2.x, q2.y), trP4), emP);
        const uint64_t c5 = pk_add(pk_add(pk2(q2.z, q2.w), trP5), emP);
        const uint64_t c6 = pk_add(pk_add(pk2(q3.x, q3.y), trP6), emP);
        const uint64_t c7 = pk_add(pk_add(pk2(q3.z, q3.w), trP7), emP);

        // Value pass: max over 16 via v_max3_f32 tree (no index tracking -> no cndmask)
        const float x0 = max3(pklo(c0), pkhi(c0), pklo(c1));
        const float x1 = max3(pkhi(c1), pklo(c2), pkhi(c2));
        const float x2 = max3(pklo(c3), pkhi(c3), pklo(c4));
        const float x3 = max3(pkhi(c4), pklo(c5), pkhi(c5));
        const float x4 = max3(pklo(c6), pkhi(c6), pklo(c7));
        const float x5 = pkhi(c7);
        const float y0 = max3(x0, x1, x2);
        const float y1 = max3(x3, x4, x5);
        const float M  = combine_max8(fmaxf(y0, y1));   // all lanes: column max

        // Index pass (EXACT np.argmax first-occurrence):
        // s' = fl(c - M): == 0 iff c == M (distinct floats never subtract to 0);
        // v = fma(s', -1e12, k): match -> exactly k; non-match -> >= ulp(M)*1e12 >> 127.
        // min(v) = smallest matching global index = first occurrence.
        const uint64_t negMP = pk2(-M, -M);
        const uint64_t v0 = pk_fma(pk_add(c0, negMP), negH, kP0);
        const uint64_t v1 = pk_fma(pk_add(c1, negMP), negH, kP1);
        const uint64_t v2 = pk_fma(pk_add(c2, negMP), negH, kP2);
        const uint64_t v3 = pk_fma(pk_add(c3, negMP), negH, kP3);
        const uint64_t v4 = pk_fma(pk_add(c4, negMP), negH, kP4);
        const uint64_t v5 = pk_fma(pk_add(c5, negMP), negH, kP5);
        const uint64_t v6 = pk_fma(pk_add(c6, negMP), negH, kP6);
        const uint64_t v7 = pk_fma(pk_add(c7, negMP), negH, kP7);
        const float z0 = min3(pklo(v0), pkhi(v0), pklo(v1));
        const float z1 = min3(pkhi(v1), pklo(v2), pkhi(v2));
        const float z2 = min3(pklo(v3), pkhi(v3), pklo(v4));
        const float z3 = min3(pkhi(v4), pklo(v5), pkhi(v5));
        const float z4 = min3(pklo(v6), pkhi(v6), pklo(v7));
        const float z5 = pkhi(v7);
        const float u0 = min3(z0, z1, z2);
        const float u1 = min3(z3, z4, z5);
        const float vmin = combine_min8(fminf(u0, u1));

        if (writer) {
            hist[t - 1][j] = (unsigned char)(int)vmin;  // exact integer < 128
            scj = maskv[t] ? M : scj;                   // where(mask, next, old)
            scbuf[p ^ 1][jslot] = scj;
        }
        // LDS-visibility barrier WITHOUT vmcnt drain (validated r7):
        asm volatile("s_waitcnt lgkmcnt(0)\n\ts_barrier" ::: "memory");
        p ^= 1;
    }

    // final = sc + end_transitions, straight from writer registers
    if (writer) fin[j] = scj + end_t[j];
    __syncthreads();

    // first-occurrence argmax over 128 tags (wave 0)
    if (tid < 64) {
        float v  = fin[tid]; int bj = tid;
        float v1 = fin[tid + 64];
        if (v1 > v) { v = v1; bj = tid + 64; }
#pragma unroll
        for (int off = 32; off > 0; off >>= 1) {
            float ov = __shfl_xor(v, off, 64);
            int   oj = __shfl_xor(bj, off, 64);
            if (ov > v || (ov == v && oj < bj)) { v = ov; bj = oj; }
        }
        if (tid == 0) { bestval_s = v; bestj_s = bj; }
    }
    __syncthreads();

    // ---- Chunked parallel backtrace: 8 chunks x 128 tags = 1 chain/thread ----
    {
        const int k = tid & 127;
        const int c = tid >> 7;        // 0..7
        int tag = k;
        for (int u = 63; u >= 0; --u) {
            const int s = c * 64 + u;
            if (s <= SLEN - 2) {
                int pv = hist[s][tag];
                tag = maskv[s + 1] ? pv : tag;
            }
        }
        exitc[c][k] = (unsigned char)tag;
    }
    __syncthreads();

    if (tid == 0) {
        int tag = bestj_s;
        for (int c = 7; c >= 0; --c) {
            st_tags[c] = (unsigned char)tag;
            tag = exitc[c][tag];
        }
        out[BATCH * SLEN + b] = bestval_s;        // best_path_score
    }
    __syncthreads();

    if (tid < 8) {
        const int c = tid;
        int tag = st_tags[c];
        if (c == 7) tagseq[SLEN - 1] = (unsigned char)tag;
        const int shi = (c == 7) ? (SLEN - 2) : (c * 64 + 63);
        for (int s = shi; s >= c * 64; --s) {
            int pv = hist[s][tag];
            tag = maskv[s + 1] ? pv : tag;
            tagseq[s] = (unsigned char)tag;
        }
    }
    __syncthreads();

    // Coalesced tag writeout as float: out0 is tags.T -> [B, S] row-major
    if (tid < SLEN)
        out[b * SLEN + tid] = (float)tagseq[tid];
}

extern "C" void kernel_launch(void* const* d_in, const int* in_sizes, int n_in,
                              void* d_out, int out_size, void* d_ws, size_t ws_size,
                              hipStream_t stream) {
    const float* em      = (const float*)d_in[0];
    const int*   mask    = (const int*)d_in[1];
    const float* start_t = (const float*)d_in[2];
    const float* end_t   = (const float*)d_in[3];
    const float* trans   = (const float*)d_in[4];
    float* out = (float*)d_out;

    viterbi_kernel<<<dim3(BATCH), dim3(NTHR), 0, stream>>>(
        em, mask, start_t, end_t, trans, out);
}

// Round 14
// 399.224 us; speedup vs baseline: 1.0508x; 1.0508x over previous
//
#include <hip/hip_runtime.h>
#include <stdint.h>

#define SLEN  512
#define BATCH 256
#define NTAGS 128
#define NTHR  1024   // j = tid>>3 (0..127), h = tid&7 -> 16 waves, 4/SIMD

// Cross-lane combine stages — ALL pure-VALU DPP now (no DS pipe).
// Value/index-split combines are order- and tie-independent (pure max / pure
// min), so any coverage pattern is exact; no XOR topology needed.
__device__ __forceinline__ int dpp_qperm_b1(int x) {  // lane <- lane^1
    return __builtin_amdgcn_update_dpp(0, x, 0xB1, 0xF, 0xF, true);
}
__device__ __forceinline__ int dpp_qperm_4e(int x) {  // lane <- lane^2
    return __builtin_amdgcn_update_dpp(0, x, 0x4E, 0xF, 0xF, true);
}
__device__ __forceinline__ int dpp_hmirror(int x) {   // lane <- (l&~7)|(7-(l&7))
    return __builtin_amdgcn_update_dpp(0, x, 0x141, 0xF, 0xF, true);
}

__device__ __forceinline__ float combine_max8(float v) {
    float vo = __int_as_float(dpp_qperm_b1(__float_as_int(v))); v = fmaxf(v, vo);
    vo = __int_as_float(dpp_qperm_4e(__float_as_int(v)));       v = fmaxf(v, vo);
    vo = __int_as_float(dpp_hmirror(__float_as_int(v)));        v = fmaxf(v, vo);
    return v;   // after quad-complete ^1,^2, half-mirror pairs the two quads
}
__device__ __forceinline__ float combine_min8(float v) {
    float vo = __int_as_float(dpp_qperm_b1(__float_as_int(v))); v = fminf(v, vo);
    vo = __int_as_float(dpp_qperm_4e(__float_as_int(v)));       v = fminf(v, vo);
    vo = __int_as_float(dpp_hmirror(__float_as_int(v)));        v = fminf(v, vo);
    return v;
}

// ---- packed 2xf32 VOP3P (gfx90a+): add/fma only (pk_max/min do not exist) ----
__device__ __forceinline__ uint64_t pk2(float lo, float hi) {
    union { float f[2]; uint64_t u; } x; x.f[0] = lo; x.f[1] = hi; return x.u;
}
__device__ __forceinline__ float pklo(uint64_t a) { return __uint_as_float((unsigned)a); }
__device__ __forceinline__ float pkhi(uint64_t a) { return __uint_as_float((unsigned)(a >> 32)); }
__device__ __forceinline__ uint64_t pk_add(uint64_t a, uint64_t b) {
    uint64_t d; asm("v_pk_add_f32 %0, %1, %2" : "=v"(d) : "v"(a), "v"(b)); return d;
}
__device__ __forceinline__ uint64_t pk_fma(uint64_t a, uint64_t b, uint64_t c) {
    uint64_t d; asm("v_pk_fma_f32 %0, %1, %2, %3" : "=v"(d) : "v"(a), "v"(b), "v"(c)); return d;
}
__device__ __forceinline__ float max3(float a, float b, float c) {
    float d; asm("v_max3_f32 %0, %1, %2, %3" : "=v"(d) : "v"(a), "v"(b), "v"(c)); return d;
}
__device__ __forceinline__ float min3(float a, float b, float c) {
    float d; asm("v_min3_f32 %0, %1, %2, %3" : "=v"(d) : "v"(a), "v"(b), "v"(c)); return d;
}

__global__ __launch_bounds__(NTHR, 4) void viterbi_kernel(
    const float* __restrict__ em,      // [S,B,T]
    const int*   __restrict__ mask,    // [S,B]
    const float* __restrict__ start_t, // [T]
    const float* __restrict__ end_t,   // [T]
    const float* __restrict__ trans,   // [T,T]
    float* __restrict__ out)           // [B*S] tags (as float), then [B] scores
{
    const int b    = blockIdx.x;
    const int tid  = threadIdx.x;
    const int j    = tid >> 3;         // 0..127
    const int h    = tid & 7;          // 0..7
    const int base = h << 4;           // h*16
    const bool writer = (h == 0);
    const int jslot = j + (j >> 4) * 4;   // chunk j>>4 at float offset (j>>4)*20

    __shared__ __align__(16) float scbuf[2][8 * 20];
    __shared__ float fin[NTAGS];
    __shared__ int   maskv[SLEN];
    __shared__ unsigned char hist[SLEN - 1][NTAGS];   // 65408 B
    __shared__ unsigned char exitc[8][NTAGS];
    __shared__ unsigned char st_tags[8];
    __shared__ unsigned char tagseq[SLEN];
    __shared__ float bestval_s;
    __shared__ int   bestj_s;

    // trans pairs: trP_m = (trans[base+2m][j], trans[base+2m+1][j])
    const float* trp = trans + (size_t)base * NTAGS + j;
    const uint64_t trP0 = pk2(trp[ 0*NTAGS], trp[ 1*NTAGS]);
    const uint64_t trP1 = pk2(trp[ 2*NTAGS], trp[ 3*NTAGS]);
    const uint64_t trP2 = pk2(trp[ 4*NTAGS], trp[ 5*NTAGS]);
    const uint64_t trP3 = pk2(trp[ 6*NTAGS], trp[ 7*NTAGS]);
    const uint64_t trP4 = pk2(trp[ 8*NTAGS], trp[ 9*NTAGS]);
    const uint64_t trP5 = pk2(trp[10*NTAGS], trp[11*NTAGS]);
    const uint64_t trP6 = pk2(trp[12*NTAGS], trp[13*NTAGS]);
    const uint64_t trP7 = pk2(trp[14*NTAGS], trp[15*NTAGS]);

    // global-index pairs (float-encoded), and the -1e12 penalty pair
    const uint64_t kP0 = pk2((float)(base +  0), (float)(base +  1));
    const uint64_t kP1 = pk2((float)(base +  2), (float)(base +  3));
    const uint64_t kP2 = pk2((float)(base +  4), (float)(base +  5));
    const uint64_t kP3 = pk2((float)(base +  6), (float)(base +  7));
    const uint64_t kP4 = pk2((float)(base +  8), (float)(base +  9));
    const uint64_t kP5 = pk2((float)(base + 10), (float)(base + 11));
    const uint64_t kP6 = pk2((float)(base + 12), (float)(base + 13));
    const uint64_t kP7 = pk2((float)(base + 14), (float)(base + 15));
    const uint64_t negH = pk2(-1e12f, -1e12f);

    if (tid < SLEN)
        maskv[tid] = mask[tid * BATCH + b];

    float scj = 0.f;
    if (writer) {
        scj = start_t[j] + em[(size_t)b * NTAGS + j];   // exact ref associativity
        scbuf[0][jslot] = scj;
    }
    __syncthreads();

    const float* emp = em + (size_t)BATCH * NTAGS + (size_t)b * NTAGS + j; // t=1
    float em_next = *emp;

    int p = 0;
    for (int t = 1; t < SLEN; ++t) {
        const float em_cur = em_next;
        if (t + 1 < SLEN) { emp += BATCH * NTAGS; em_next = *emp; }

        // 16 sc values as 8 adjacent pairs (4 broadcast b128 reads)
        const float4* sq = (const float4*)&scbuf[p][h * 20];
        const float4 q0 = sq[0], q1 = sq[1], q2 = sq[2], q3 = sq[3];

        // c_k = fl(fl(sc+tr)+em): 2 candidates per v_pk_add_f32 (bit-exact per half)
        const uint64_t emP = pk2(em_cur, em_cur);
        const uint64_t c0 = pk_add(pk_add(pk2(q0.x, q0.y), trP0), emP);
        const uint64_t c1 = pk_add(pk_add(pk2(q0.z, q0.w), trP1), emP);
        const uint64_t c2 = pk_add(pk_add(pk2(q1.x, q1.y), trP2), emP);
        const uint64_t c3 = pk_add(pk_add(pk2(q1.z, q1.w), trP3), emP);
        const uint64_t c4 = pk_add(pk_add(pk2(q2.x, q2.y), trP4), emP);
        const uint64_t c5 = pk_add(pk_add(pk2(q2.z, q2.w), trP5), emP);
        const uint64_t c6 = pk_add(pk_add(pk2(q3.x, q3.y), trP6), emP);
        const uint64_t c7 = pk_add(pk_add(pk2(q3.z, q3.w), trP7), emP);

        // Value pass: max over 16 via v_max3_f32 tree
        const float x0 = max3(pklo(c0), pkhi(c0), pklo(c1));
        const float x1 = max3(pkhi(c1), pklo(c2), pkhi(c2));
        const float x2 = max3(pklo(c3), pkhi(c3), pklo(c4));
        const float x3 = max3(pkhi(c4), pklo(c5), pkhi(c5));
        const float x4 = max3(pklo(c6), pkhi(c6), pklo(c7));
        const float x5 = pkhi(c7);
        const float y0 = max3(x0, x1, x2);
        const float y1 = max3(x3, x4, x5);
        const float M  = combine_max8(fmaxf(y0, y1));   // all lanes: column max

        // Index pass (EXACT np.argmax first-occurrence):
        // s' = fl(c - M): == 0 iff c == M; v = fma(s', -1e12, k): match -> exactly k,
        // non-match -> >= ulp(M)*1e12 >> 127. min(v) = first-occurrence index.
        const uint64_t negMP = pk2(-M, -M);
        const uint64_t v0 = pk_fma(pk_add(c0, negMP), negH, kP0);
        const uint64_t v1 = pk_fma(pk_add(c1, negMP), negH, kP1);
        const uint64_t v2 = pk_fma(pk_add(c2, negMP), negH, kP2);
        const uint64_t v3 = pk_fma(pk_add(c3, negMP), negH, kP3);
        const uint64_t v4 = pk_fma(pk_add(c4, negMP), negH, kP4);
        const uint64_t v5 = pk_fma(pk_add(c5, negMP), negH, kP5);
        const uint64_t v6 = pk_fma(pk_add(c6, negMP), negH, kP6);
        const uint64_t v7 = pk_fma(pk_add(c7, negMP), negH, kP7);
        const float z0 = min3(pklo(v0), pkhi(v0), pklo(v1));
        const float z1 = min3(pkhi(v1), pklo(v2), pkhi(v2));
        const float z2 = min3(pklo(v3), pkhi(v3), pklo(v4));
        const float z3 = min3(pkhi(v4), pklo(v5), pkhi(v5));
        const float z4 = min3(pklo(v6), pkhi(v6), pklo(v7));
        const float z5 = pkhi(v7);
        const float u0 = min3(z0, z1, z2);
        const float u1 = min3(z3, z4, z5);
        const float vmin = combine_min8(fminf(u0, u1));

        if (writer) {
            hist[t - 1][j] = (unsigned char)(int)vmin;  // exact integer < 128
            scj = maskv[t] ? M : scj;                   // where(mask, next, old)
            scbuf[p ^ 1][jslot] = scj;
        }
        // LDS-visibility barrier WITHOUT vmcnt drain (validated r7):
        asm volatile("s_waitcnt lgkmcnt(0)\n\ts_barrier" ::: "memory");
        p ^= 1;
    }

    // final = sc + end_transitions, straight from writer registers
    if (writer) fin[j] = scj + end_t[j];
    __syncthreads();

    // first-occurrence argmax over 128 tags (wave 0)
    if (tid < 64) {
        float v  = fin[tid]; int bj = tid;
        float v1 = fin[tid + 64];
        if (v1 > v) { v = v1; bj = tid + 64; }
#pragma unroll
        for (int off = 32; off > 0; off >>= 1) {
            float ov = __shfl_xor(v, off, 64);
            int   oj = __shfl_xor(bj, off, 64);
            if (ov > v || (ov == v && oj < bj)) { v = ov; bj = oj; }
        }
        if (tid == 0) { bestval_s = v; bestj_s = bj; }
    }
    __syncthreads();

    // ---- Chunked parallel backtrace: 8 chunks x 128 tags = 1 chain/thread ----
    {
        const int k = tid & 127;
        const int c = tid >> 7;        // 0..7
        int tag = k;
        for (int u = 63; u >= 0; --u) {
            const int s = c * 64 + u;
            if (s <= SLEN - 2) {
                int pv = hist[s][tag];
                tag = maskv[s + 1] ? pv : tag;
            }
        }
        exitc[c][k] = (unsigned char)tag;
    }
    __syncthreads();

    if (tid == 0) {
        int tag = bestj_s;
        for (int c = 7; c >= 0; --c) {
            st_tags[c] = (unsigned char)tag;
            tag = exitc[c][tag];
        }
        out[BATCH * SLEN + b] = bestval_s;        // best_path_score
    }
    __syncthreads();

    if (tid < 8) {
        const int c = tid;
        int tag = st_tags[c];
        if (c == 7) tagseq[SLEN - 1] = (unsigned char)tag;
        const int shi = (c == 7) ? (SLEN - 2) : (c * 64 + 63);
        for (int s = shi; s >= c * 64; --s) {
            int pv = hist[s][tag];
            tag = maskv[s + 1] ? pv : tag;
            tagseq[s] = (unsigned char)tag;
        }
    }
    __syncthreads();

    // Coalesced tag writeout as float: out0 is tags.T -> [B, S] row-major
    if (tid < SLEN)
        out[b * SLEN + tid] = (float)tagseq[tid];
}

extern "C" void kernel_launch(void* const* d_in, const int* in_sizes, int n_in,
                              void* d_out, int out_size, void* d_ws, size_t ws_size,
                              hipStream_t stream) {
    const float* em      = (const float*)d_in[0];
    const int*   mask    = (const int*)d_in[1];
    const float* start_t = (const float*)d_in[2];
    const float* end_t   = (const float*)d_in[3];
    const float* trans   = (const float*)d_in[4];
    float* out = (float*)d_out;

    viterbi_kernel<<<dim3(BATCH), dim3(NTHR), 0, stream>>>(
        em, mask, start_t, end_t, trans, out);
}

// Round 15
// 389.454 us; speedup vs baseline: 1.0771x; 1.0251x over previous
//
#include <hip/hip_runtime.h>

#define SLEN  512
#define BATCH 256
#define NTAGS 128
#define NTHR  1024   // j = tid>>3 (0..127), h = tid&7 -> 16 waves, 4/SIMD

// Pure-VALU DPP cross-lane combines (validated bit-exact r14).
// Value/index-split combines are pure max / pure min -> order-independent.
__device__ __forceinline__ int dpp_qperm_b1(int x) {  // lane <- lane^1
    return __builtin_amdgcn_update_dpp(0, x, 0xB1, 0xF, 0xF, true);
}
__device__ __forceinline__ int dpp_qperm_4e(int x) {  // lane <- lane^2
    return __builtin_amdgcn_update_dpp(0, x, 0x4E, 0xF, 0xF, true);
}
__device__ __forceinline__ int dpp_hmirror(int x) {   // lane <- (l&~7)|(7-(l&7))
    return __builtin_amdgcn_update_dpp(0, x, 0x141, 0xF, 0xF, true);
}

__device__ __forceinline__ float combine_max8(float v) {
    float vo = __int_as_float(dpp_qperm_b1(__float_as_int(v))); v = fmaxf(v, vo);
    vo = __int_as_float(dpp_qperm_4e(__float_as_int(v)));       v = fmaxf(v, vo);
    vo = __int_as_float(dpp_hmirror(__float_as_int(v)));        v = fmaxf(v, vo);
    return v;
}
__device__ __forceinline__ float combine_min8(float v) {
    float vo = __int_as_float(dpp_qperm_b1(__float_as_int(v))); v = fminf(v, vo);
    vo = __int_as_float(dpp_qperm_4e(__float_as_int(v)));       v = fminf(v, vo);
    vo = __int_as_float(dpp_hmirror(__float_as_int(v)));        v = fminf(v, vo);
    return v;
}

// 3-input max/min: single VALU inst each (gfx950 ISA sec.3). Scalar floats only
// -> zero register-pair marshalling (r13/r14's uint64 path emitted ~2x inst).
__device__ __forceinline__ float max3(float a, float b, float c) {
    float d; asm("v_max3_f32 %0, %1, %2, %3" : "=v"(d) : "v"(a), "v"(b), "v"(c)); return d;
}
__device__ __forceinline__ float min3(float a, float b, float c) {
    float d; asm("v_min3_f32 %0, %1, %2, %3" : "=v"(d) : "v"(a), "v"(b), "v"(c)); return d;
}

__global__ __launch_bounds__(NTHR, 4) void viterbi_kernel(
    const float* __restrict__ em,      // [S,B,T]
    const int*   __restrict__ mask,    // [S,B]
    const float* __restrict__ start_t, // [T]
    const float* __restrict__ end_t,   // [T]
    const float* __restrict__ trans,   // [T,T]
    float* __restrict__ out)           // [B*S] tags (as float), then [B] scores
{
    const int b    = blockIdx.x;
    const int tid  = threadIdx.x;
    const int j    = tid >> 3;         // 0..127
    const int h    = tid & 7;          // 0..7
    const int base = h << 4;           // h*16
    const bool writer = (h == 0);
    const int jslot = j + (j >> 4) * 4;   // chunk j>>4 at float offset (j>>4)*20

    __shared__ __align__(16) float scbuf[2][8 * 20];
    __shared__ float fin[NTAGS];
    __shared__ int   maskv[SLEN];
    __shared__ unsigned char hist[SLEN - 1][NTAGS];   // 65408 B
    __shared__ unsigned char exitc[8][NTAGS];
    __shared__ unsigned char st_tags[8];
    __shared__ unsigned char tagseq[SLEN];
    __shared__ float bestval_s;
    __shared__ int   bestj_s;

    // 16 named scalar transition regs: tXX = trans[base+k][j]
    const float* trp = trans + (size_t)base * NTAGS + j;
    const float t00 = trp[ 0*NTAGS], t01 = trp[ 1*NTAGS], t02 = trp[ 2*NTAGS], t03 = trp[ 3*NTAGS];
    const float t04 = trp[ 4*NTAGS], t05 = trp[ 5*NTAGS], t06 = trp[ 6*NTAGS], t07 = trp[ 7*NTAGS];
    const float t08 = trp[ 8*NTAGS], t09 = trp[ 9*NTAGS], t10 = trp[10*NTAGS], t11 = trp[11*NTAGS];
    const float t12 = trp[12*NTAGS], t13 = trp[13*NTAGS], t14 = trp[14*NTAGS], t15 = trp[15*NTAGS];

    // float-encoded global indices for the index pass
    const float k00 = (float)(base +  0), k01 = (float)(base +  1);
    const float k02 = (float)(base +  2), k03 = (float)(base +  3);
    const float k04 = (float)(base +  4), k05 = (float)(base +  5);
    const float k06 = (float)(base +  6), k07 = (float)(base +  7);
    const float k08 = (float)(base +  8), k09 = (float)(base +  9);
    const float k10 = (float)(base + 10), k11 = (float)(base + 11);
    const float k12 = (float)(base + 12), k13 = (float)(base + 13);
    const float k14 = (float)(base + 14), k15 = (float)(base + 15);
    const float NH = -1e12f;

    if (tid < SLEN)
        maskv[tid] = mask[tid * BATCH + b];

    float scj = 0.f;
    if (writer) {
        scj = start_t[j] + em[(size_t)b * NTAGS + j];   // exact ref associativity
        scbuf[0][jslot] = scj;
    }
    __syncthreads();

    const float* emp = em + (size_t)BATCH * NTAGS + (size_t)b * NTAGS + j; // t=1
    float em_next = *emp;

    int p = 0;
    for (int t = 1; t < SLEN; ++t) {
        const float em_cur = em_next;
        if (t + 1 < SLEN) { emp += BATCH * NTAGS; em_next = *emp; }

        // 16 sc values: 4 broadcast b128 reads
        const float4* sq = (const float4*)&scbuf[p][h * 20];
        const float4 q0 = sq[0], q1 = sq[1], q2 = sq[2], q3 = sq[3];

        // c_k = fl(fl(sc+tr)+em) — exact ref associativity, all named scalars
        const float c00 = (q0.x + t00) + em_cur, c01 = (q0.y + t01) + em_cur;
        const float c02 = (q0.z + t02) + em_cur, c03 = (q0.w + t03) + em_cur;
        const float c04 = (q1.x + t04) + em_cur, c05 = (q1.y + t05) + em_cur;
        const float c06 = (q1.z + t06) + em_cur, c07 = (q1.w + t07) + em_cur;
        const float c08 = (q2.x + t08) + em_cur, c09 = (q2.y + t09) + em_cur;
        const float c10 = (q2.z + t10) + em_cur, c11 = (q2.w + t11) + em_cur;
        const float c12 = (q3.x + t12) + em_cur, c13 = (q3.y + t13) + em_cur;
        const float c14 = (q3.z + t14) + em_cur, c15 = (q3.w + t15) + em_cur;

        // Value pass: pure max (order-free; ties share identical bits)
        const float x0 = max3(c00, c01, c02);
        const float x1 = max3(c03, c04, c05);
        const float x2 = max3(c06, c07, c08);
        const float x3 = max3(c09, c10, c11);
        const float x4 = max3(c12, c13, c14);
        const float y0 = max3(x0, x1, x2);
        const float y1 = max3(x3, x4, c15);
        const float M  = combine_max8(fmaxf(y0, y1));   // all lanes: column max

        // Index pass (EXACT np.argmax first-occurrence):
        // s = fl(c - M) == 0 iff c == M (min nonzero |c-M| = ulp(M) >> denormal);
        // v = fma(s, -1e12, k): match -> exactly k; else >= ulp(M)*1e12 >> 127.
        // min(v) = smallest matching index = first occurrence (incl. all ties).
        const float v00 = fmaf(c00 - M, NH, k00), v01 = fmaf(c01 - M, NH, k01);
        const float v02 = fmaf(c02 - M, NH, k02), v03 = fmaf(c03 - M, NH, k03);
        const float v04 = fmaf(c04 - M, NH, k04), v05 = fmaf(c05 - M, NH, k05);
        const float v06 = fmaf(c06 - M, NH, k06), v07 = fmaf(c07 - M, NH, k07);
        const float v08 = fmaf(c08 - M, NH, k08), v09 = fmaf(c09 - M, NH, k09);
        const float v10 = fmaf(c10 - M, NH, k10), v11 = fmaf(c11 - M, NH, k11);
        const float v12 = fmaf(c12 - M, NH, k12), v13 = fmaf(c13 - M, NH, k13);
        const float v14 = fmaf(c14 - M, NH, k14), v15 = fmaf(c15 - M, NH, k15);
        const float z0 = min3(v00, v01, v02);
        const float z1 = min3(v03, v04, v05);
        const float z2 = min3(v06, v07, v08);
        const float z3 = min3(v09, v10, v11);
        const float z4 = min3(v12, v13, v14);
        const float u0 = min3(z0, z1, z2);
        const float u1 = min3(z3, z4, v15);
        const float vmin = combine_min8(fminf(u0, u1));

        if (writer) {
            hist[t - 1][j] = (unsigned char)(int)vmin;  // exact integer < 128
            scj = maskv[t] ? M : scj;                   // where(mask, next, old)
            scbuf[p ^ 1][jslot] = scj;
        }
        // LDS-visibility barrier WITHOUT vmcnt drain (validated r7):
        asm volatile("s_waitcnt lgkmcnt(0)\n\ts_barrier" ::: "memory");
        p ^= 1;
    }

    // final = sc + end_transitions, straight from writer registers
    if (writer) fin[j] = scj + end_t[j];
    __syncthreads();

    // first-occurrence argmax over 128 tags (wave 0)
    if (tid < 64) {
        float v  = fin[tid]; int bj = tid;
        float v1 = fin[tid + 64];
        if (v1 > v) { v = v1; bj = tid + 64; }
#pragma unroll
        for (int off = 32; off > 0; off >>= 1) {
            float ov = __shfl_xor(v, off, 64);
            int   oj = __shfl_xor(bj, off, 64);
            if (ov > v || (ov == v && oj < bj)) { v = ov; bj = oj; }
        }
        if (tid == 0) { bestval_s = v; bestj_s = bj; }
    }
    __syncthreads();

    // ---- Chunked parallel backtrace: 8 chunks x 128 tags = 1 chain/thread ----
    {
        const int k = tid & 127;
        const int c = tid >> 7;        // 0..7
        int tag = k;
        for (int u = 63; u >= 0; --u) {
            const int s = c * 64 + u;
            if (s <= SLEN - 2) {
                int pv = hist[s][tag];
                tag = maskv[s + 1] ? pv : tag;
            }
        }
        exitc[c][k] = (unsigned char)tag;
    }
    __syncthreads();

    if (tid == 0) {
        int tag = bestj_s;
        for (int c = 7; c >= 0; --c) {
            st_tags[c] = (unsigned char)tag;
            tag = exitc[c][tag];
        }
        out[BATCH * SLEN + b] = bestval_s;        // best_path_score
    }
    __syncthreads();

    if (tid < 8) {
        const int c = tid;
        int tag = st_tags[c];
        if (c == 7) tagseq[SLEN - 1] = (unsigned char)tag;
        const int shi = (c == 7) ? (SLEN - 2) : (c * 64 + 63);
        for (int s = shi; s >= c * 64; --s) {
            int pv = hist[s][tag];
            tag = maskv[s + 1] ? pv : tag;
            tagseq[s] = (unsigned char)tag;
        }
    }
    __syncthreads();

    // Coalesced tag writeout as float: out0 is tags.T -> [B, S] row-major
    if (tid < SLEN)
        out[b * SLEN + tid] = (float)tagseq[tid];
}

extern "C" void kernel_launch(void* const* d_in, const int* in_sizes, int n_in,
                              void* d_out, int out_size, void* d_ws, size_t ws_size,
                              hipStream_t stream) {
    const float* em      = (const float*)d_in[0];
    const int*   mask    = (const int*)d_in[1];
    const float* start_t = (const float*)d_in[2];
    const float* end_t   = (const float*)d_in[3];
    const float* trans   = (const float*)d_in[4];
    float* out = (float*)d_out;

    viterbi_kernel<<<dim3(BATCH), dim3(NTHR), 0, stream>>>(
        em, mask, start_t, end_t, trans, out);
}